// Round 1
// 774.475 us; speedup vs baseline: 1.0814x; 1.0814x over previous
//
#include <hip/hip_runtime.h>

#define IN_DIM 512
#define BATCH  512
#define NCLS   100000
#define NC     10
#define NTILE  782   // 128-column tiles per row (782*128 = 100096 >= 100000)

using half8_t  = __attribute__((ext_vector_type(8))) _Float16;
using floatx4  = __attribute__((ext_vector_type(4))) float;

// ---------------------------------------------------------------------------
// K1: row norms of x, f16 hi/lo split (x scaled by 16), y-dtype detection
// ---------------------------------------------------------------------------
__global__ __launch_bounds__(256) void k_prep(const float* __restrict__ x,
                                              const int* __restrict__ yraw,
                                              _Float16* __restrict__ xhi,
                                              _Float16* __restrict__ xlo,
                                              float* __restrict__ invx,
                                              int* __restrict__ yflag) {
  int b = blockIdx.x, t = threadIdx.x;
  __shared__ float red[256];
  float v0 = x[b * IN_DIM + t];
  float v1 = x[b * IN_DIM + t + 256];
  red[t] = v0 * v0 + v1 * v1;
  __syncthreads();
  for (int s = 128; s > 0; s >>= 1) {
    if (t < s) red[t] += red[t + s];
    __syncthreads();
  }
  if (t == 0) invx[b] = 1.0f / fmaxf(sqrtf(red[0]), 1e-12f);

  float s0 = v0 * 16.f, s1 = v1 * 16.f;
  _Float16 h0 = (_Float16)s0, h1 = (_Float16)s1;
  xhi[b * IN_DIM + t]       = h0;
  xhi[b * IN_DIM + t + 256] = h1;
  xlo[b * IN_DIM + t]       = (_Float16)(s0 - (float)h0);
  xlo[b * IN_DIM + t + 256] = (_Float16)(s1 - (float)h1);

  if (b == 0 && t == 0) {
    // int64 little-endian layout => every odd 32-bit word is 0
    int allz = 1;
    for (int i = 1; i < 512; i += 2) allz &= (yraw[i] == 0);
    *yflag = allz;
  }
}

// ---------------------------------------------------------------------------
// K2: split-f16 MFMA GEMM, 128x128 tiles, BK=32, fused column norms.
//     v2: XCD-chunked block swizzle (4 row-siblings share one XCD's L2 so W
//     is fetched once), register prefetch of next K-tile under the MFMA
//     phase (T14), and fused per-(row, col-tile) max (excluding class y)
//     for the pruned top-k pass.
// ---------------------------------------------------------------------------
__global__ __launch_bounds__(256, 3) void k_gemm(const _Float16* __restrict__ xhi,
                                                 const _Float16* __restrict__ xlo,
                                                 const float* __restrict__ W,
                                                 const float* __restrict__ invx,
                                                 const int* __restrict__ yraw,
                                                 const int* __restrict__ yflag,
                                                 float* __restrict__ tilemax,
                                                 float* __restrict__ out) {
  __shared__ half8_t lAhi[512], lAlo[512], lBhi[512], lBlo[512];  // 8KB each
  __shared__ float   ssred[512];
  __shared__ float   invwn[128];
  __shared__ int     clsb[128];

  const int t = threadIdx.x;
  // XCD-chunked bijective swizzle: 3128 blocks = 8 XCDs * 391 slots.
  // HW assigns XCD = blockIdx % 8; give each XCD a contiguous run of
  // column tiles with the 4 row-siblings adjacent -> W slab read once/L2.
  const int bid = blockIdx.x;
  const int g2  = (bid & 7) * 391 + (bid >> 3);
  const int ct  = g2 >> 2;          // column tile 0..781
  const int m0  = (g2 & 3) * 128;   // row tile
  const int c0  = ct * 128;

  const int g    = t >> 6;          // wave id = k-subgroup for B staging
  const int lane = t & 63;
  const int cpl  = lane * 2;        // local column pair base (even)
  const bool cval = (c0 + cpl) < NCLS;

  const int w  = t >> 6;
  const int ll = t & 63;
  const int wm = ((w >> 1) & 1) * 64;
  const int wn = (w & 1) * 64;
  const int ko = ll >> 4, lm = ll & 15;

  if (t < 128) clsb[t] = (*yflag) ? yraw[2 * (m0 + t)] : yraw[m0 + t];

  floatx4 acc[4][4] = {};
  float ss0 = 0.f, ss1 = 0.f;

  // register prefetch buffers (filled during MFMA phase of previous K-step)
  half8_t ahR[2], alR[2];
  float2  wv[8];

  auto loadA = [&](int ks) {
#pragma unroll
    for (int h = 0; h < 2; h++) {
      int p = t + h * 256;
      size_t off = (size_t)(m0 + (p & 127)) * IN_DIM + (size_t)(ks * 32 + (p >> 7) * 8);
      ahR[h] = *(const half8_t*)(xhi + off);
      alR[h] = *(const half8_t*)(xlo + off);
    }
  };
  auto loadB = [&](int ks) {
    const float* wp = W + (size_t)(ks * 32 + g * 8) * NCLS + (c0 + cpl);
#pragma unroll
    for (int r = 0; r < 8; r++) {
      wv[r] = cval ? *(const float2*)(wp + (size_t)r * NCLS) : make_float2(0.f, 0.f);
    }
  };

  loadA(0);
  loadB(0);

  for (int ks = 0; ks < 16; ks++) {
    // ---- phase 1: LDS stores from prefetched regs (convert + sumsq) ----
#pragma unroll
    for (int h = 0; h < 2; h++) {
      int p = t + h * 256;
      lAhi[p] = ahR[h];
      lAlo[p] = alR[h];
    }
    half8_t b0h, b0l, b1h, b1l;
#pragma unroll
    for (int r = 0; r < 8; r++) {
      float w0 = wv[r].x, w1 = wv[r].y;
      ss0 += w0 * w0;
      ss1 += w1 * w1;
      float sw0 = w0 * 256.f, sw1 = w1 * 256.f;
      _Float16 h0 = (_Float16)sw0, h1 = (_Float16)sw1;
      b0h[r] = h0; b1h[r] = h1;
      b0l[r] = (_Float16)(sw0 - (float)h0);
      b1l[r] = (_Float16)(sw1 - (float)h1);
    }
    {
      // interleaved chunk swizzle: chunk(c) = (c&1)*64 + (c>>1) (within g-block)
      int bi0 = g * 128 + (cpl >> 1);
      lBhi[bi0] = b0h; lBhi[bi0 + 64] = b1h;
      lBlo[bi0] = b0l; lBlo[bi0 + 64] = b1l;
    }
    __syncthreads();

    // ---- phase 2: issue next tile's global loads, then compute ----
    // Loads stay in flight under ds_read + 48 MFMAs; the bottom barrier's
    // vmcnt(0) drain lands exactly where the data is next consumed.
    if (ks < 15) { loadA(ks + 1); loadB(ks + 1); }

    half8_t ah[4], al[4], bh[4], bl[4];
#pragma unroll
    for (int i = 0; i < 4; i++) {
      int am = wm + i * 16 + lm;
      ah[i] = lAhi[ko * 128 + am];
      al[i] = lAlo[ko * 128 + am];
      int cl = wn + i * 16 + lm;
      int bidx = ko * 128 + ((cl & 1) << 6) + (cl >> 1);
      bh[i] = lBhi[bidx];
      bl[i] = lBlo[bidx];
    }
#pragma unroll
    for (int i = 0; i < 4; i++)
#pragma unroll
      for (int j = 0; j < 4; j++) {
        acc[i][j] = __builtin_amdgcn_mfma_f32_16x16x32_f16(ah[i], bh[j], acc[i][j], 0, 0, 0);
        acc[i][j] = __builtin_amdgcn_mfma_f32_16x16x32_f16(ah[i], bl[j], acc[i][j], 0, 0, 0);
        acc[i][j] = __builtin_amdgcn_mfma_f32_16x16x32_f16(al[i], bh[j], acc[i][j], 0, 0, 0);
      }
    __syncthreads();
  }

  // ---- column inv-norms (fp32 sums over full K gathered from 4 waves) ----
  ssred[cpl * 4 + g]       = ss0;
  ssred[(cpl + 1) * 4 + g] = ss1;
  __syncthreads();
  if (t < 128) {
    float s = ssred[t * 4] + ssred[t * 4 + 1] + ssred[t * 4 + 2] + ssred[t * 4 + 3];
    invwn[t] = (1.0f / 4096.0f) / fmaxf(sqrtf(s), 1e-12f);  // folds x*16, W*256 scales
  }
  __syncthreads();

  // ---- epilogue: C write + per-row tile max (excluding class y) ----
  float rmax[4][4];
#pragma unroll
  for (int i = 0; i < 4; i++)
#pragma unroll
    for (int rr = 0; rr < 4; rr++) rmax[i][rr] = -3.402823466e38f;

#pragma unroll
  for (int i = 0; i < 4; i++) {
#pragma unroll
    for (int rr = 0; rr < 4; rr++) {
      int rl = wm + i * 16 + ko * 4 + rr;   // C/D layout: col=lane&15, row=(lane>>4)*4+reg
      int rg = m0 + rl;
      float ix = invx[rg];
      int mycls = clsb[rl];
#pragma unroll
      for (int j = 0; j < 4; j++) {
        int cl = wn + j * 16 + lm;
        int cg = c0 + cl;
        if (cg < NCLS) {
          float v = acc[i][j][rr] * ix * invwn[cl];
          v = fminf(fmaxf(v, -1.f), 1.f) * 64.f;
          out[(size_t)rg * NCLS + cg] = v;
          if (cg != mycls) rmax[i][rr] = fmaxf(rmax[i][rr], v);
        }
      }
    }
  }
  // reduce across the 16-lane group that shares each row
#pragma unroll
  for (int i = 0; i < 4; i++)
#pragma unroll
    for (int rr = 0; rr < 4; rr++) {
#pragma unroll
      for (int off = 1; off < 16; off <<= 1)
        rmax[i][rr] = fmaxf(rmax[i][rr], __shfl_xor(rmax[i][rr], off));
    }
  if (lm == 0) {
#pragma unroll
    for (int i = 0; i < 4; i++)
#pragma unroll
      for (int rr = 0; rr < 4; rr++)
        ssred[(wm + i * 16 + ko * 4 + rr) * 2 + (w & 1)] = rmax[i][rr];  // ssred reuse
  }
  __syncthreads();
  if (t < 128)
    tilemax[(size_t)(m0 + t) * NTILE + ct] = fmaxf(ssred[t * 2], ssred[t * 2 + 1]);
}

// ---------------------------------------------------------------------------
// K3: exact fp32 target cosine, intra_scores, angular-margin logit at y[b]
// ---------------------------------------------------------------------------
__global__ __launch_bounds__(256) void k_fix(const float* __restrict__ x,
                                             const float* __restrict__ W,
                                             const int* __restrict__ yraw,
                                             const int* __restrict__ yflag,
                                             const float* __restrict__ invx,
                                             float* __restrict__ out) {
  int b = blockIdx.x, t = threadIdx.x;
  int cls = (*yflag) ? yraw[2 * b] : yraw[b];
  __shared__ float rd[256], rs[256];
  float dot = 0.f, ssw = 0.f;
#pragma unroll
  for (int h = 0; h < 2; h++) {
    int k   = t + h * 256;
    float xv = x[b * IN_DIM + k];
    float wv = W[(size_t)k * NCLS + cls];
    dot += xv * wv;
    ssw += wv * wv;
  }
  rd[t] = dot; rs[t] = ssw;
  __syncthreads();
  for (int s = 128; s > 0; s >>= 1) {
    if (t < s) { rd[t] += rd[t + s]; rs[t] += rs[t + s]; }
    __syncthreads();
  }
  if (t == 0) {
    float iw  = 1.0f / fmaxf(sqrtf(rs[0]), 1e-12f);
    float tgt = rd[0] * invx[b] * iw;
    tgt = fminf(fmaxf(tgt, -1.f), 1.f);
    out[(size_t)BATCH * NCLS + b] = tgt;  // intra_scores
    const float cosM = 0.87758256189037271612f;   // cos(0.5)
    const float sinM = 0.47942553860420300027f;   // sin(0.5)
    float mc;
    if (tgt > -cosM)   // theta < pi - M
      mc = tgt * cosM - sqrtf(fmaxf(1.f - tgt * tgt, 0.f)) * sinM;
    else
      mc = tgt - sinM * 0.5f;
    out[(size_t)b * NCLS + cls] = 64.f * mc;
  }
}

// ---------------------------------------------------------------------------
// K4: pruned top-10 per row using per-tile maxes.
//     tau = 10th-largest tile max; since those 10 maxes ARE 10 distinct
//     candidate elements, true 10th element >= tau, so tiles with
//     max < tau provably cannot contribute. Scan only surviving tiles
//     (~10 of 782) -> ~1.3 KB read per row instead of 400 KB.
// ---------------------------------------------------------------------------
__global__ __launch_bounds__(256) void k_topk(const float* __restrict__ logits,
                                              const float* __restrict__ tmaxArr,
                                              const int* __restrict__ yraw,
                                              const int* __restrict__ yflag,
                                              float* __restrict__ outIdx) {
  const int b = blockIdx.x, t = threadIdx.x;
  const int cls = (*yflag) ? yraw[2 * b] : yraw[b];
  const float* tm = tmaxArr + (size_t)b * NTILE;

  __shared__ float lv[2560];
  __shared__ int   li[2560];
  __shared__ float cv[256];
  __shared__ int   ci[256];
  __shared__ int   cp[256];
  __shared__ int   list[NTILE];
  __shared__ int   cnt;
  __shared__ float stau;

  float vals[10]; int idxs[10];
#pragma unroll
  for (int i = 0; i < 10; i++) { vals[i] = -3.402823466e38f; idxs[i] = 0x7fffffff; }

  // ---- stage 1: per-thread top-10 of tile maxes -> tau ----
  for (int T = t; T < NTILE; T += 256) {
    float v = tm[T];
    if (v > vals[9] || (v == vals[9] && T < idxs[9])) {
      float cv2 = v; int ci2 = T;
#pragma unroll
      for (int p = 0; p < 10; p++) {
        bool better = (cv2 > vals[p]) || (cv2 == vals[p] && ci2 < idxs[p]);
        if (better) {
          float tv = vals[p]; int ti = idxs[p];
          vals[p] = cv2; idxs[p] = ci2;
          cv2 = tv; ci2 = ti;
        }
      }
    }
  }
#pragma unroll
  for (int i = 0; i < 10; i++) { lv[t * 10 + i] = vals[i]; li[t * 10 + i] = idxs[i]; }
  if (t == 0) cnt = 0;
  __syncthreads();

  for (int r = 0; r < NC; r++) {
    float bv = -3.402823466e38f; int bi = 0x7fffffff; int bp = -1;
#pragma unroll
    for (int i = 0; i < 10; i++) {
      int e = t * 10 + i;
      float v = lv[e];
      if (v > bv || (v == bv && li[e] < bi)) { bv = v; bi = li[e]; bp = e; }
    }
    cv[t] = bv; ci[t] = bi; cp[t] = bp;
    __syncthreads();
    for (int s = 128; s > 0; s >>= 1) {
      if (t < s) {
        if (cv[t + s] > cv[t] || (cv[t + s] == cv[t] && ci[t + s] < ci[t])) {
          cv[t] = cv[t + s]; ci[t] = ci[t + s]; cp[t] = cp[t + s];
        }
      }
      __syncthreads();
    }
    if (t == 0) {
      lv[cp[0]] = -3.402823466e38f;
      if (r == NC - 1) stau = cv[0];
    }
    __syncthreads();
  }
  const float tau = stau;

  // ---- stage 2: collect candidate tiles (max >= tau, ties included) ----
  for (int T = t; T < NTILE; T += 256)
    if (tm[T] >= tau) { int p = atomicAdd(&cnt, 1); list[p] = T; }
  __syncthreads();
  const int n = cnt;

  // ---- stage 3: scan candidate tiles' logits, exact top-10 ----
#pragma unroll
  for (int i = 0; i < 10; i++) { vals[i] = -3.402823466e38f; idxs[i] = 0x7fffffff; }
  const float* row = logits + (size_t)b * NCLS;
  for (int kk = t; kk < n * 128; kk += 256) {
    int T = list[kk >> 7];
    int c = T * 128 + (kk & 127);
    if (c >= NCLS || c == cls) continue;
    float v = row[c];
    if (v > vals[9] || (v == vals[9] && c < idxs[9])) {
      float cv2 = v; int ci2 = c;
#pragma unroll
      for (int p = 0; p < 10; p++) {
        bool better = (cv2 > vals[p]) || (cv2 == vals[p] && ci2 < idxs[p]);
        if (better) {
          float tv = vals[p]; int ti = idxs[p];
          vals[p] = cv2; idxs[p] = ci2;
          cv2 = tv; ci2 = ti;
        }
      }
    }
  }
#pragma unroll
  for (int i = 0; i < 10; i++) { lv[t * 10 + i] = vals[i]; li[t * 10 + i] = idxs[i]; }
  __syncthreads();

  for (int r = 0; r < NC; r++) {
    float bv = -3.402823466e38f; int bi = 0x7fffffff; int bp = -1;
#pragma unroll
    for (int i = 0; i < 10; i++) {
      int e = t * 10 + i;
      float v = lv[e];
      if (v > bv || (v == bv && li[e] < bi)) { bv = v; bi = li[e]; bp = e; }
    }
    cv[t] = bv; ci[t] = bi; cp[t] = bp;
    __syncthreads();
    for (int s = 128; s > 0; s >>= 1) {
      if (t < s) {
        if (cv[t + s] > cv[t] || (cv[t + s] == cv[t] && ci[t + s] < ci[t])) {
          cv[t] = cv[t + s]; ci[t] = ci[t + s]; cp[t] = cp[t + s];
        }
      }
      __syncthreads();
    }
    if (t == 0) {
      outIdx[b * NC + r] = (float)ci[0];
      lv[cp[0]] = -3.402823466e38f;
    }
    __syncthreads();
  }
}

// ---------------------------------------------------------------------------
extern "C" void kernel_launch(void* const* d_in, const int* in_sizes, int n_in,
                              void* d_out, int out_size, void* d_ws, size_t ws_size,
                              hipStream_t stream) {
  const float* x = (const float*)d_in[0];
  const float* W = (const float*)d_in[1];
  const int*   y = (const int*)d_in[2];
  // d_in[3] = nc (=10) — hardcoded; host cannot read device scalar under capture
  float* out = (float*)d_out;
  char*  ws  = (char*)d_ws;

  _Float16* xhi  = (_Float16*)ws;                       // 512 KB
  _Float16* xlo  = (_Float16*)(ws + (1 << 19));         // 512 KB
  float*    invx = (float*)(ws + (1 << 20));            // 2 KB
  int*      yfl  = (int*)(ws + (1 << 20) + 4096);       // 4 B
  float*    tmax = (float*)(ws + (1 << 20) + 8192);     // 512*782*4 = 1.53 MB

  k_prep<<<BATCH, 256, 0, stream>>>(x, y, xhi, xlo, invx, yfl);
  k_gemm<<<dim3(8 * 391), 256, 0, stream>>>(xhi, xlo, W, invx, y, yfl, tmax, out);
  k_fix<<<BATCH, 256, 0, stream>>>(x, W, y, yfl, invx, out);
  k_topk<<<BATCH, 256, 0, stream>>>(out, tmax, y, yfl, out + (size_t)BATCH * NCLS + BATCH);
}

// Round 2
// 636.906 us; speedup vs baseline: 1.3149x; 1.2160x over previous
//
#include <hip/hip_runtime.h>

#define IN_DIM 512
#define BATCH  512
#define NCLS   100000
#define NC     10
#define NTILE  782   // 128-column tiles per row (782*128 = 100096 >= 100000)

using half8_t  = __attribute__((ext_vector_type(8))) _Float16;
using floatx4  = __attribute__((ext_vector_type(4))) float;

// ---------------------------------------------------------------------------
// K1: row norms of x, f16 hi/lo split (x scaled by 16), y-dtype detection
// ---------------------------------------------------------------------------
__global__ __launch_bounds__(256) void k_prep(const float* __restrict__ x,
                                              const int* __restrict__ yraw,
                                              _Float16* __restrict__ xhi,
                                              _Float16* __restrict__ xlo,
                                              float* __restrict__ invx,
                                              int* __restrict__ yflag) {
  int b = blockIdx.x, t = threadIdx.x;
  __shared__ float red[256];
  float v0 = x[b * IN_DIM + t];
  float v1 = x[b * IN_DIM + t + 256];
  red[t] = v0 * v0 + v1 * v1;
  __syncthreads();
  for (int s = 128; s > 0; s >>= 1) {
    if (t < s) red[t] += red[t + s];
    __syncthreads();
  }
  if (t == 0) invx[b] = 1.0f / fmaxf(sqrtf(red[0]), 1e-12f);

  float s0 = v0 * 16.f, s1 = v1 * 16.f;
  _Float16 h0 = (_Float16)s0, h1 = (_Float16)s1;
  xhi[b * IN_DIM + t]       = h0;
  xhi[b * IN_DIM + t + 256] = h1;
  xlo[b * IN_DIM + t]       = (_Float16)(s0 - (float)h0);
  xlo[b * IN_DIM + t + 256] = (_Float16)(s1 - (float)h1);

  if (b == 0 && t == 0) {
    // int64 little-endian layout => every odd 32-bit word is 0
    int allz = 1;
    for (int i = 1; i < 512; i += 2) allz &= (yraw[i] == 0);
    *yflag = allz;
  }
}

// ---------------------------------------------------------------------------
// K2: split-f16 MFMA GEMM, 128x128 tiles, BK=32, fused column norms.
//     Round-0 proven inner-loop structure (loads at top of K-step, converts
//     interleaved with progressive vmcnt waits — compiler schedules this
//     well; explicit reg-prefetch measured -45%).
//     Kept from v2: XCD-chunked block swizzle (FETCH 406->147 MB measured),
//     fused per-(row, col-tile) max excluding class y (transposed layout
//     [tile][row] -> full-line 512B writes, no 32x amplification).
// ---------------------------------------------------------------------------
__global__ __launch_bounds__(256, 2) void k_gemm(const _Float16* __restrict__ xhi,
                                                 const _Float16* __restrict__ xlo,
                                                 const float* __restrict__ W,
                                                 const float* __restrict__ invx,
                                                 const int* __restrict__ yraw,
                                                 const int* __restrict__ yflag,
                                                 float* __restrict__ tilemax,
                                                 float* __restrict__ out) {
  __shared__ half8_t lAhi[512], lAlo[512], lBhi[512], lBlo[512];  // 8KB each
  __shared__ float   ssred[512];
  __shared__ float   invwn[128];
  __shared__ int     clsb[128];

  const int t = threadIdx.x;
  // XCD-chunked bijective swizzle: 3128 blocks = 8 XCDs * 391 slots.
  // HW assigns XCD = blockIdx % 8; give each XCD a contiguous run of
  // column tiles with the 4 row-siblings adjacent -> W slab fetched into
  // one L2 and hit by the other 3 siblings.
  const int bid = blockIdx.x;
  const int g2  = (bid & 7) * 391 + (bid >> 3);
  const int ct  = g2 >> 2;          // column tile 0..781
  const int m0  = (g2 & 3) * 128;   // row tile
  const int c0  = ct * 128;

  const int g    = t >> 6;          // wave id = k-subgroup for B staging
  const int lane = t & 63;
  const int cpl  = lane * 2;        // local column pair base (even)
  const bool cval = (c0 + cpl) < NCLS;

  const int w  = t >> 6;
  const int ll = t & 63;
  const int wm = ((w >> 1) & 1) * 64;
  const int wn = (w & 1) * 64;
  const int ko = ll >> 4, lm = ll & 15;

  if (t < 128) clsb[t] = (*yflag) ? yraw[2 * (m0 + t)] : yraw[m0 + t];

  floatx4 acc[4][4] = {};
  float ss0 = 0.f, ss1 = 0.f;

  for (int ks = 0; ks < 16; ks++) {
    const int k0 = ks * 32;
    // ---- A staging (direct vector copy; layout [ko][m], 16B chunks) ----
#pragma unroll
    for (int h = 0; h < 2; h++) {
      int p  = t + h * 256;
      int pk = p >> 7, pm = p & 127;
      size_t off = (size_t)(m0 + pm) * IN_DIM + (size_t)(k0 + pk * 8);
      lAhi[p] = *(const half8_t*)(xhi + off);
      lAlo[p] = *(const half8_t*)(xlo + off);
    }
    // ---- B staging: transpose W tile, scale x256, f16 split, sumsq ----
    half8_t b0h, b0l, b1h, b1l;
#pragma unroll
    for (int r = 0; r < 8; r++) {
      float w0 = 0.f, w1 = 0.f;
      if (cval) {
        const float2 wv = *(const float2*)(W + (size_t)(k0 + g * 8 + r) * NCLS + (c0 + cpl));
        w0 = wv.x; w1 = wv.y;
      }
      ss0 += w0 * w0;
      ss1 += w1 * w1;
      float sw0 = w0 * 256.f, sw1 = w1 * 256.f;
      _Float16 h0 = (_Float16)sw0, h1 = (_Float16)sw1;
      b0h[r] = h0; b1h[r] = h1;
      b0l[r] = (_Float16)(sw0 - (float)h0);
      b1l[r] = (_Float16)(sw1 - (float)h1);
    }
    {
      // interleaved chunk swizzle: chunk(c) = (c&1)*64 + (c>>1)  (within g-block)
      int bi0 = g * 128 + (cpl >> 1);
      lBhi[bi0] = b0h; lBhi[bi0 + 64] = b1h;
      lBlo[bi0] = b0l; lBlo[bi0 + 64] = b1l;
    }
    __syncthreads();

    // ---- fragments + 3-pass MFMA ----
    half8_t ah[4], al[4], bh[4], bl[4];
#pragma unroll
    for (int i = 0; i < 4; i++) {
      int am = wm + i * 16 + lm;
      ah[i] = lAhi[ko * 128 + am];
      al[i] = lAlo[ko * 128 + am];
      int cl = wn + i * 16 + lm;
      int bidx = ko * 128 + ((cl & 1) << 6) + (cl >> 1);
      bh[i] = lBhi[bidx];
      bl[i] = lBlo[bidx];
    }
#pragma unroll
    for (int i = 0; i < 4; i++)
#pragma unroll
      for (int j = 0; j < 4; j++) {
        acc[i][j] = __builtin_amdgcn_mfma_f32_16x16x32_f16(ah[i], bh[j], acc[i][j], 0, 0, 0);
        acc[i][j] = __builtin_amdgcn_mfma_f32_16x16x32_f16(ah[i], bl[j], acc[i][j], 0, 0, 0);
        acc[i][j] = __builtin_amdgcn_mfma_f32_16x16x32_f16(al[i], bh[j], acc[i][j], 0, 0, 0);
      }
    __syncthreads();
  }

  // ---- column inv-norms (fp32 sums over full K gathered from 4 waves) ----
  ssred[cpl * 4 + g]       = ss0;
  ssred[(cpl + 1) * 4 + g] = ss1;
  __syncthreads();
  if (t < 128) {
    float s = ssred[t * 4] + ssred[t * 4 + 1] + ssred[t * 4 + 2] + ssred[t * 4 + 3];
    invwn[t] = (1.0f / 4096.0f) / fmaxf(sqrtf(s), 1e-12f);  // folds x*16, W*256 scales
  }
  __syncthreads();

  // ---- epilogue: C write + per-row tile max (excluding class y) ----
  float rmax[4][4];
#pragma unroll
  for (int i = 0; i < 4; i++)
#pragma unroll
    for (int rr = 0; rr < 4; rr++) rmax[i][rr] = -3.402823466e38f;

#pragma unroll
  for (int i = 0; i < 4; i++) {
#pragma unroll
    for (int rr = 0; rr < 4; rr++) {
      int rl = wm + i * 16 + ko * 4 + rr;   // C/D layout: col=lane&15, row=(lane>>4)*4+reg
      int rg = m0 + rl;
      float ix = invx[rg];
      int mycls = clsb[rl];
#pragma unroll
      for (int j = 0; j < 4; j++) {
        int cl = wn + j * 16 + lm;
        int cg = c0 + cl;
        if (cg < NCLS) {
          float v = acc[i][j][rr] * ix * invwn[cl];
          v = fminf(fmaxf(v, -1.f), 1.f) * 64.f;
          out[(size_t)rg * NCLS + cg] = v;
          if (cg != mycls) rmax[i][rr] = fmaxf(rmax[i][rr], v);
        }
      }
    }
  }
  // reduce across the 16-lane group that shares each row
#pragma unroll
  for (int i = 0; i < 4; i++)
#pragma unroll
    for (int rr = 0; rr < 4; rr++) {
#pragma unroll
      for (int off = 1; off < 16; off <<= 1)
        rmax[i][rr] = fmaxf(rmax[i][rr], __shfl_xor(rmax[i][rr], off));
    }
  if (lm == 0) {
#pragma unroll
    for (int i = 0; i < 4; i++)
#pragma unroll
      for (int rr = 0; rr < 4; rr++)
        ssred[(wm + i * 16 + ko * 4 + rr) * 2 + (w & 1)] = rmax[i][rr];  // ssred reuse
  }
  __syncthreads();
  // transposed layout [tile][row]: 128 consecutive floats per block = full lines
  if (t < 128)
    tilemax[(size_t)ct * BATCH + m0 + t] = fmaxf(ssred[t * 2], ssred[t * 2 + 1]);
}

// ---------------------------------------------------------------------------
// K3: exact fp32 target cosine, intra_scores, angular-margin logit at y[b]
// ---------------------------------------------------------------------------
__global__ __launch_bounds__(256) void k_fix(const float* __restrict__ x,
                                             const float* __restrict__ W,
                                             const int* __restrict__ yraw,
                                             const int* __restrict__ yflag,
                                             const float* __restrict__ invx,
                                             float* __restrict__ out) {
  int b = blockIdx.x, t = threadIdx.x;
  int cls = (*yflag) ? yraw[2 * b] : yraw[b];
  __shared__ float rd[256], rs[256];
  float dot = 0.f, ssw = 0.f;
#pragma unroll
  for (int h = 0; h < 2; h++) {
    int k   = t + h * 256;
    float xv = x[b * IN_DIM + k];
    float wv = W[(size_t)k * NCLS + cls];
    dot += xv * wv;
    ssw += wv * wv;
  }
  rd[t] = dot; rs[t] = ssw;
  __syncthreads();
  for (int s = 128; s > 0; s >>= 1) {
    if (t < s) { rd[t] += rd[t + s]; rs[t] += rs[t + s]; }
    __syncthreads();
  }
  if (t == 0) {
    float iw  = 1.0f / fmaxf(sqrtf(rs[0]), 1e-12f);
    float tgt = rd[0] * invx[b] * iw;
    tgt = fminf(fmaxf(tgt, -1.f), 1.f);
    out[(size_t)BATCH * NCLS + b] = tgt;  // intra_scores
    const float cosM = 0.87758256189037271612f;   // cos(0.5)
    const float sinM = 0.47942553860420300027f;   // sin(0.5)
    float mc;
    if (tgt > -cosM)   // theta < pi - M
      mc = tgt * cosM - sqrtf(fmaxf(1.f - tgt * tgt, 0.f)) * sinM;
    else
      mc = tgt - sinM * 0.5f;
    out[(size_t)b * NCLS + cls] = 64.f * mc;
  }
}

// ---------------------------------------------------------------------------
// K4: pruned top-10 per row using per-tile maxes (tilemax layout [tile][row]).
//     tau = 10th-largest tile max; since those 10 maxes ARE 10 distinct
//     candidate elements, true 10th element >= tau, so tiles with
//     max < tau provably cannot contribute. Scan only surviving tiles
//     (~10 of 782) -> ~1.3 KB read per row instead of 400 KB.
// ---------------------------------------------------------------------------
__global__ __launch_bounds__(256) void k_topk(const float* __restrict__ logits,
                                              const float* __restrict__ tmaxArr,
                                              const int* __restrict__ yraw,
                                              const int* __restrict__ yflag,
                                              float* __restrict__ outIdx) {
  const int b = blockIdx.x, t = threadIdx.x;
  const int cls = (*yflag) ? yraw[2 * b] : yraw[b];

  __shared__ float lv[2560];
  __shared__ int   li[2560];
  __shared__ float cv[256];
  __shared__ int   ci[256];
  __shared__ int   cp[256];
  __shared__ int   list[NTILE];
  __shared__ int   cnt;
  __shared__ float stau;

  float vals[10]; int idxs[10];
#pragma unroll
  for (int i = 0; i < 10; i++) { vals[i] = -3.402823466e38f; idxs[i] = 0x7fffffff; }

  // ---- stage 1: per-thread top-10 of tile maxes -> tau ----
  for (int T = t; T < NTILE; T += 256) {
    float v = tmaxArr[(size_t)T * BATCH + b];
    if (v > vals[9] || (v == vals[9] && T < idxs[9])) {
      float cv2 = v; int ci2 = T;
#pragma unroll
      for (int p = 0; p < 10; p++) {
        bool better = (cv2 > vals[p]) || (cv2 == vals[p] && ci2 < idxs[p]);
        if (better) {
          float tv = vals[p]; int ti = idxs[p];
          vals[p] = cv2; idxs[p] = ci2;
          cv2 = tv; ci2 = ti;
        }
      }
    }
  }
#pragma unroll
  for (int i = 0; i < 10; i++) { lv[t * 10 + i] = vals[i]; li[t * 10 + i] = idxs[i]; }
  if (t == 0) cnt = 0;
  __syncthreads();

  for (int r = 0; r < NC; r++) {
    float bv = -3.402823466e38f; int bi = 0x7fffffff; int bp = -1;
#pragma unroll
    for (int i = 0; i < 10; i++) {
      int e = t * 10 + i;
      float v = lv[e];
      if (v > bv || (v == bv && li[e] < bi)) { bv = v; bi = li[e]; bp = e; }
    }
    cv[t] = bv; ci[t] = bi; cp[t] = bp;
    __syncthreads();
    for (int s = 128; s > 0; s >>= 1) {
      if (t < s) {
        if (cv[t + s] > cv[t] || (cv[t + s] == cv[t] && ci[t + s] < ci[t])) {
          cv[t] = cv[t + s]; ci[t] = ci[t + s]; cp[t] = cp[t + s];
        }
      }
      __syncthreads();
    }
    if (t == 0) {
      lv[cp[0]] = -3.402823466e38f;
      if (r == NC - 1) stau = cv[0];
    }
    __syncthreads();
  }
  const float tau = stau;

  // ---- stage 2: collect candidate tiles (max >= tau, ties included) ----
  for (int T = t; T < NTILE; T += 256)
    if (tmaxArr[(size_t)T * BATCH + b] >= tau) { int p = atomicAdd(&cnt, 1); list[p] = T; }
  __syncthreads();
  const int n = cnt;

  // ---- stage 3: scan candidate tiles' logits, exact top-10 ----
#pragma unroll
  for (int i = 0; i < 10; i++) { vals[i] = -3.402823466e38f; idxs[i] = 0x7fffffff; }
  const float* row = logits + (size_t)b * NCLS;
  for (int kk = t; kk < n * 128; kk += 256) {
    int T = list[kk >> 7];
    int c = T * 128 + (kk & 127);
    if (c >= NCLS || c == cls) continue;
    float v = row[c];
    if (v > vals[9] || (v == vals[9] && c < idxs[9])) {
      float cv2 = v; int ci2 = c;
#pragma unroll
      for (int p = 0; p < 10; p++) {
        bool better = (cv2 > vals[p]) || (cv2 == vals[p] && ci2 < idxs[p]);
        if (better) {
          float tv = vals[p]; int ti = idxs[p];
          vals[p] = cv2; idxs[p] = ci2;
          cv2 = tv; ci2 = ti;
        }
      }
    }
  }
#pragma unroll
  for (int i = 0; i < 10; i++) { lv[t * 10 + i] = vals[i]; li[t * 10 + i] = idxs[i]; }
  __syncthreads();

  for (int r = 0; r < NC; r++) {
    float bv = -3.402823466e38f; int bi = 0x7fffffff; int bp = -1;
#pragma unroll
    for (int i = 0; i < 10; i++) {
      int e = t * 10 + i;
      float v = lv[e];
      if (v > bv || (v == bv && li[e] < bi)) { bv = v; bi = li[e]; bp = e; }
    }
    cv[t] = bv; ci[t] = bi; cp[t] = bp;
    __syncthreads();
    for (int s = 128; s > 0; s >>= 1) {
      if (t < s) {
        if (cv[t + s] > cv[t] || (cv[t + s] == cv[t] && ci[t + s] < ci[t])) {
          cv[t] = cv[t + s]; ci[t] = ci[t + s]; cp[t] = cp[t + s];
        }
      }
      __syncthreads();
    }
    if (t == 0) {
      outIdx[b * NC + r] = (float)ci[0];
      lv[cp[0]] = -3.402823466e38f;
    }
    __syncthreads();
  }
}

// ---------------------------------------------------------------------------
extern "C" void kernel_launch(void* const* d_in, const int* in_sizes, int n_in,
                              void* d_out, int out_size, void* d_ws, size_t ws_size,
                              hipStream_t stream) {
  const float* x = (const float*)d_in[0];
  const float* W = (const float*)d_in[1];
  const int*   y = (const int*)d_in[2];
  // d_in[3] = nc (=10) — hardcoded; host cannot read device scalar under capture
  float* out = (float*)d_out;
  char*  ws  = (char*)d_ws;

  _Float16* xhi  = (_Float16*)ws;                       // 512 KB
  _Float16* xlo  = (_Float16*)(ws + (1 << 19));         // 512 KB
  float*    invx = (float*)(ws + (1 << 20));            // 2 KB
  int*      yfl  = (int*)(ws + (1 << 20) + 4096);       // 4 B
  float*    tmax = (float*)(ws + (1 << 20) + 8192);     // 782*512*4 = 1.53 MB

  k_prep<<<BATCH, 256, 0, stream>>>(x, y, xhi, xlo, invx, yfl);
  k_gemm<<<dim3(8 * 391), 256, 0, stream>>>(xhi, xlo, W, invx, y, yfl, tmax, out);
  k_fix<<<BATCH, 256, 0, stream>>>(x, W, y, yfl, invx, out);
  k_topk<<<BATCH, 256, 0, stream>>>(out, tmax, y, yfl, out + (size_t)BATCH * NCLS + BATCH);
}